// Round 5
// baseline (220.409 us; speedup 1.0000x reference)
//
#include <hip/hip_runtime.h>
#include <hip/hip_fp16.h>

// FeatureAdaption (DCNv1). B=4, CIN=COUT=128, H=W=128, K=3, G=4, CG=32.
// Round 5: wave-independent deform conv.
//  - grid 1024: block = (b, h, half-row of 64 px); 4 blocks/CU.
//  - wave wv owns N-tile nt=wv (16 px). Lane map cq=lane>>4, px=16wv+(lane&15)
//    puts the gathered bilinear value directly in B-frag lane position:
//    NO B-frag LDS round-trip, NO per-kk barriers (16 barriers total).
//  - K=32 MFMA via even/odd 16-ch chunk pairing in registers; channel
//    permutation pi(k) baked into wdef A-frags: k=8q+j -> c = j<4 ? 4q+j
//    : 16+4q+(j-4). B h8 = concat(bhold[kk], bnew).
//  - xs staged from x f32 via 4ch x 4px register transpose + pkrtz; row
//    stride 74 uint2 (bank decorrelation + 16B-aligned b128 writes).
//
// ws layout (bytes): wdef [0,294912) | woff [294912,315392) | offs2 [315392,9752576)

#define HW 16384

typedef _Float16 h2 __attribute__((ext_vector_type(2)));
typedef _Float16 h4 __attribute__((ext_vector_type(4)));
typedef _Float16 h8 __attribute__((ext_vector_type(8)));
typedef float floatx4 __attribute__((ext_vector_type(4)));

static __device__ __forceinline__ unsigned pkrtz(float a, float b) {
  auto h = __builtin_amdgcn_cvt_pkrtz(a, b);
  return __builtin_bit_cast(unsigned, h);
}
static __device__ __forceinline__ h2 u2h2(unsigned u) { return __builtin_bit_cast(h2, u); }
static __device__ __forceinline__ h2 splat_lo(unsigned u) {
  unsigned v = (u & 0xffffu) | (u << 16); return u2h2(v);
}
static __device__ __forceinline__ h2 splat_hi(unsigned u) {
  unsigned v = (u >> 16) | (u & 0xffff0000u); return u2h2(v);
}

// ---------------- kernel 0: weight prep ----------------
__global__ __launch_bounds__(256) void prep_w(
    const float* __restrict__ w_off, const float* __restrict__ w_def,
    _Float16* __restrict__ woff, _Float16* __restrict__ wdef) {
  int idx = blockIdx.x * 256 + threadIdx.x;
  int stride = gridDim.x * 256;
  // wdef A-frags (16x16x32, permuted k): [kk9][scp4][ot8][lane64][j8]
  //   o = ot*16 + (lane&15); c = scp*32 + (j<4 ? 4q+j : 16+4q+(j-4)), q=lane>>4
  for (int i = idx; i < 147456; i += stride) {
    int j = i & 7, l = (i >> 3) & 63, ot = (i >> 9) & 7, scp = (i >> 12) & 3, kk = i >> 14;
    int q = l >> 4;
    int c = scp * 32 + ((j < 4) ? (4 * q + j) : (16 + 4 * q + (j - 4)));
    int o = ot * 16 + (l & 15);
    wdef[i] = (_Float16)w_def[(o * 128 + c) * 9 + kk];
  }
  // woff A-frags (16x16x32, standard k): [ks4][mt5][lane64][j8], rows>=72 zero
  for (int i = idx; i < 10240; i += stride) {
    int j = i & 7, l = (i >> 3) & 63, t = i >> 9;
    int mt = t % 5, ks = t / 5;
    int o = mt * 16 + (l & 15);
    int c = ks * 32 + ((l >> 4) << 3) + j;
    woff[i] = (o < 72) ? (_Float16)w_off[o * 128 + c] : (_Float16)0.f;
  }
}

// ---------------- kernel 1: offset conv, f16 MFMA ----------------
// block = (b,h) row; float4-staged 4x4 reg transpose -> LDS [cq32][px128] uint2
__global__ __launch_bounds__(256) void offset_conv(
    const float* __restrict__ x, const _Float16* __restrict__ woff,
    const float* __restrict__ b_off, unsigned* __restrict__ offs2) {
  __shared__ uint2 xpk[32 * 128];   // 32 KB
  int tid = threadIdx.x, lane = tid & 63, wv = tid >> 6;
  int i = blockIdx.x;
  int L = (i & 7) * 64 + (i >> 3);  // XCD band swizzle
  int b = L >> 7, h = L & 127;

#pragma unroll
  for (int it = 0; it < 4; it++) {
    int u = it * 256 + tid;
    int px4 = u & 31, cqq = u >> 5;   // 32 px-quads x 32 ch-quads
    const float* xp = x + (((size_t)b * 128 + cqq * 4) * 128 + h) * 128 + px4 * 4;
    float4 v0 = *(const float4*)xp;
    float4 v1 = *(const float4*)(xp + HW);
    float4 v2 = *(const float4*)(xp + 2 * HW);
    float4 v3 = *(const float4*)(xp + 3 * HW);
    uint2* dst = &xpk[cqq * 128 + px4 * 4];
    uint2 w;
    w.x = pkrtz(v0.x, v1.x); w.y = pkrtz(v2.x, v3.x); dst[0] = w;
    w.x = pkrtz(v0.y, v1.y); w.y = pkrtz(v2.y, v3.y); dst[1] = w;
    w.x = pkrtz(v0.z, v1.z); w.y = pkrtz(v2.z, v3.z); dst[2] = w;
    w.x = pkrtz(v0.w, v1.w); w.y = pkrtz(v2.w, v3.w); dst[3] = w;
  }
  __syncthreads();

  floatx4 acc[5][2];
#pragma unroll
  for (int mt = 0; mt < 5; mt++) { acc[mt][0] = (floatx4)0.f; acc[mt][1] = (floatx4)0.f; }
  const h8* A = (const h8*)woff;
  int quad = lane >> 4, col = lane & 15;
#pragma unroll
  for (int ks = 0; ks < 4; ks++) {
#pragma unroll
    for (int nn = 0; nn < 2; nn++) {
      int px = (2 * wv + nn) * 16 + col;
      int cq2 = ks * 8 + quad * 2;
      uint2 lo = xpk[cq2 * 128 + px];
      uint2 hi = xpk[(cq2 + 1) * 128 + px];
      uint4 q; q.x = lo.x; q.y = lo.y; q.z = hi.x; q.w = hi.y;
      h8 bv = __builtin_bit_cast(h8, q);
#pragma unroll
      for (int mt = 0; mt < 5; mt++)
        acc[mt][nn] = __builtin_amdgcn_mfma_f32_16x16x32_f16(A[(ks * 5 + mt) * 64 + lane], bv, acc[mt][nn], 0, 0, 0);
    }
  }
  // epilogue: rows o = mt*16+quad*4+reg; pack (dy,dx) o-pairs as half2
#pragma unroll
  for (int mt = 0; mt < 5; mt++) {
    if (mt == 4 && quad >= 2) continue;   // rows 72..79 are padding
    int o0 = mt * 16 + quad * 4;
    float4 bo = *(const float4*)(b_off + o0);
#pragma unroll
    for (int nn = 0; nn < 2; nn++) {
      floatx4 f = acc[mt][nn];
      int pp = (2 * wv + nn) * 16 + col;
      unsigned* dst = offs2 + ((size_t)b * 36 + (o0 >> 1)) * HW + h * 128 + pp;
      dst[0]  = pkrtz(f[0] + bo.x, f[1] + bo.y);
      dst[HW] = pkrtz(f[2] + bo.z, f[3] + bo.w);
    }
  }
}

// ---------------- kernel 2: deform conv, wave-independent ----------------
__global__ __launch_bounds__(256, 4) void deform_conv(
    const float* __restrict__ x, const _Float16* __restrict__ wdef,
    const unsigned* __restrict__ offs2, float* __restrict__ out) {
  __shared__ uint2 xs[4 * 7 * 74];        // 16576 B: [cq4][r7][74] f16 quads
  __shared__ unsigned rec_a[4][9][16];    // per-wave slices
  __shared__ uint2 rec_w[4][9][16];

  int tid = threadIdx.x, lane = tid & 63, wv = tid >> 6;
  int i = blockIdx.x;
  int L = (i & 7) * 128 + (i >> 3);       // XCD band swizzle (64 rows/XCD)
  int half = L & 1, h = (L >> 1) & 127, b = L >> 8;
  int p0 = half * 64;
  int rlo = min(max(h - 3, 0), 121);      // staged rows rlo..rlo+6
  int cs = p0 - 4;                         // staged col start (global px)
  int pxl = lane & 15, cq = lane >> 4;

  floatx4 acc[8];
#pragma unroll
  for (int ot = 0; ot < 8; ot++) acc[ot] = (floatx4)0.f;
  h4 bhold[9];

  for (int t = 0; t < 4; t++) {           // 32-ch pair group == deform group g
    // ---- per-wave records for group t (no barrier needed: own slice) ----
#pragma unroll
    for (int it = 0; it < 3; it++) {
      int u = lane + 64 * it;
      if (u < 144) {
        int kk = u >> 4, pl = u & 15;
        int p = p0 + 16 * wv + pl;
        unsigned dd = offs2[((size_t)b * 36 + t * 9 + kk) * HW + h * 128 + p];
        h2 d = u2h2(dd);
        float dy = (float)d[0], dx = (float)d[1];
        float py = (float)h + (float)(kk / 3 - 1) + dy;
        float pxs = (float)p + (float)(kk % 3 - 1) + dx;
        float y0f = floorf(py), x0f = floorf(pxs);
        int y0 = (int)y0f, x0 = (int)x0f;
        float wy1 = py - y0f, wx1 = pxs - x0f;
        float wy0 = 1.f - wy1, wx0 = 1.f - wx1;
        int x1 = x0 + 1, y1 = y0 + 1;
        int xb = min(max(x0, 0), 126);
        float fx0 = (x0 >= 0 && x0 <= 127) ? 1.f : 0.f;
        float fx1 = (x1 >= 0 && x1 <= 127) ? 1.f : 0.f;
        float wA = (x0 == xb ? wx0 * fx0 : 0.f) + (x1 == xb ? wx1 * fx1 : 0.f);
        float wB = (x0 == xb + 1 ? wx0 * fx0 : 0.f) + (x1 == xb + 1 ? wx1 * fx1 : 0.f);
        float fy0 = (y0 >= 0 && y0 <= 127) ? 1.f : 0.f;
        float fy1 = (y1 >= 0 && y1 <= 127) ? 1.f : 0.f;
        int r0 = min(max(min(max(y0, 0), 127) - rlo, 0), 6);
        int r1 = min(max(min(max(y1, 0), 127) - rlo, 0), 6);
        int lx = min(max(xb - cs, 0), 70);
        rec_a[wv][kk][pl] = (unsigned)(r0 * 74 + lx) | ((unsigned)(r1 * 74 + lx) << 16);
        uint2 rw;
        rw.x = pkrtz(wy0 * fy0, wy1 * fy1);
        rw.y = pkrtz(wA, wB);
        rec_w[wv][kk][pl] = rw;
      }
    }
#pragma unroll
    for (int e = 0; e < 2; e++) {
      int sc = 2 * t + e;
      __syncthreads();                     // prior gathers done before xs overwrite
      // ---- stage x[b][16ch][rlo..+6][cs..cs+71] -> xs (4ch x 4px transpose) ----
#pragma unroll
      for (int it = 0; it < 2; it++) {
        int u = tid + it * 256;
        if (u < 504) {
          int g4 = u % 18;                 // 4-px group (72 cols)
          int r = (u / 18) % 7;
          int c4 = u / 126;                // channel-quad 0..3
          int sp = min(max(cs + 4 * g4, 0), 124);  // edge clamp (clamped cols never read)
          const float* xp = x + (((size_t)b * 128 + sc * 16 + c4 * 4) * 128 + (rlo + r)) * 128 + sp;
          float4 v0 = *(const float4*)xp;
          float4 v1 = *(const float4*)(xp + HW);
          float4 v2 = *(const float4*)(xp + 2 * HW);
          float4 v3 = *(const float4*)(xp + 3 * HW);
          uint2* dst = &xs[(c4 * 7 + r) * 74 + 4 * g4];
          uint2 w;
          w.x = pkrtz(v0.x, v1.x); w.y = pkrtz(v2.x, v3.x); dst[0] = w;
          w.x = pkrtz(v0.y, v1.y); w.y = pkrtz(v2.y, v3.y); dst[1] = w;
          w.x = pkrtz(v0.z, v1.z); w.y = pkrtz(v2.z, v3.z); dst[2] = w;
          w.x = pkrtz(v0.w, v1.w); w.y = pkrtz(v2.w, v3.w); dst[3] = w;
        }
      }
      __syncthreads();
      // ---- per-wave gather (+ MFMA on odd chunks) ----
      const uint2* base = &xs[cq * 518];   // 7*74 per cq
      if (e == 0) {
#pragma unroll
        for (int kk = 0; kk < 9; kk++) {
          unsigned aw = rec_a[wv][kk][pxl];
          uint2 rw = rec_w[wv][kk][pxl];
          int a0 = aw & 0xffff, a1 = aw >> 16;
          h2 wy0 = splat_lo(rw.x), wy1 = splat_hi(rw.x);
          h2 wA = splat_lo(rw.y), wB = splat_hi(rw.y);
          uint2 P = base[a0], Q = base[a0 + 1], R = base[a1], S = base[a1 + 1];
          h2 u0 = wy0 * (wA * u2h2(P.x) + wB * u2h2(Q.x)) + wy1 * (wA * u2h2(R.x) + wB * u2h2(S.x));
          h2 u1 = wy0 * (wA * u2h2(P.y) + wB * u2h2(Q.y)) + wy1 * (wA * u2h2(R.y) + wB * u2h2(S.y));
          bhold[kk] = __builtin_shufflevector(u0, u1, 0, 1, 2, 3);
        }
      } else {
        const h8* Av = (const h8*)wdef;
#pragma unroll
        for (int kk = 0; kk < 9; kk++) {
          unsigned aw = rec_a[wv][kk][pxl];
          uint2 rw = rec_w[wv][kk][pxl];
          int a0 = aw & 0xffff, a1 = aw >> 16;
          h2 wy0 = splat_lo(rw.x), wy1 = splat_hi(rw.x);
          h2 wA = splat_lo(rw.y), wB = splat_hi(rw.y);
          uint2 P = base[a0], Q = base[a0 + 1], R = base[a1], S = base[a1 + 1];
          h2 u0 = wy0 * (wA * u2h2(P.x) + wB * u2h2(Q.x)) + wy1 * (wA * u2h2(R.x) + wB * u2h2(S.x));
          h2 u1 = wy0 * (wA * u2h2(P.y) + wB * u2h2(Q.y)) + wy1 * (wA * u2h2(R.y) + wB * u2h2(S.y));
          h4 bnew = __builtin_shufflevector(u0, u1, 0, 1, 2, 3);
          h8 bv = __builtin_shufflevector(bhold[kk], bnew, 0, 1, 2, 3, 4, 5, 6, 7);
          const h8* Ak = Av + (size_t)((kk * 4 + t) * 8) * 64;
#pragma unroll
          for (int ot = 0; ot < 8; ot++)
            acc[ot] = __builtin_amdgcn_mfma_f32_16x16x32_f16(Ak[ot * 64 + lane], bv, acc[ot], 0, 0, 0);
        }
      }
    }
  }

  // ---- epilogue: C/D col=lane&15 (px), row=quad*4+reg (o); ReLU ----
  int quad = lane >> 4;
  float* ob = out + (size_t)b * 128 * HW + h * 128 + p0 + 16 * wv + pxl;
#pragma unroll
  for (int ot = 0; ot < 8; ot++) {
    floatx4 f = acc[ot];
#pragma unroll
    for (int reg = 0; reg < 4; reg++) {
      int o = ot * 16 + quad * 4 + reg;
      ob[(size_t)o * HW] = fmaxf(f[reg], 0.f);
    }
  }
}

extern "C" void kernel_launch(void* const* d_in, const int* in_sizes, int n_in,
                              void* d_out, int out_size, void* d_ws, size_t ws_size,
                              hipStream_t stream) {
  const float* x     = (const float*)d_in[0];
  const float* w_off = (const float*)d_in[1];
  const float* b_off = (const float*)d_in[2];
  const float* w_def = (const float*)d_in[3];
  float* out = (float*)d_out;

  _Float16* wdef = (_Float16*)d_ws;                          // 294912 B
  _Float16* woff = (_Float16*)((char*)d_ws + 294912);        // 20480 B
  unsigned* offs2 = (unsigned*)((char*)d_ws + 315392);       // 9437184 B

  hipLaunchKernelGGL(prep_w, dim3(288), dim3(256), 0, stream, w_off, w_def, woff, wdef);
  hipLaunchKernelGGL(offset_conv, dim3(512), dim3(256), 0, stream, x, woff, b_off, offs2);
  hipLaunchKernelGGL(deform_conv, dim3(1024), dim3(256), 0, stream, x, wdef, offs2, out);
}

// Round 6
// 191.034 us; speedup vs baseline: 1.1538x; 1.1538x over previous
//
#include <hip/hip_runtime.h>
#include <hip/hip_fp16.h>

// FeatureAdaption (DCNv1). B=4, CIN=COUT=128, H=W=128, K=3, G=4, CG=32.
// Round 6: round-4 skeleton + three fixes (no register pairing — round 5's
// bhold scheme spilled ~170 MB to scratch, WRITE_SIZE 198 MB vs 32 MB output).
//  - grid 1024: block = (b, h, half-row 64 px); LDS 48.2 KB -> 3 blocks/CU.
//  - per group t (=deform group g, 32 ch): stage 32ch x 7r x 72px slab of x
//    into LDS as f16 octets xs4[r][px][slot] (uint4 = 8 ch), slot swizzled
//    (dq+px+(px>>2))&3 to spread bank quads.
//  - gather: 4 x ds_read_b128 per thread -> one full K=32 B-frag uint4,
//    written to double-buffered bfrag; MFMA 16x16x32_f16 (full rate).
//  - records (bilinear addr+weights) once per group, 9kk x 64px in LDS.
//
// ws layout (bytes): wdef [0,294912) | woff [294912,315392) | offs2 [315392,9752576)

#define HW 16384

typedef _Float16 h2 __attribute__((ext_vector_type(2)));
typedef _Float16 h8 __attribute__((ext_vector_type(8)));
typedef float floatx4 __attribute__((ext_vector_type(4)));

static __device__ __forceinline__ unsigned pkrtz(float a, float b) {
  auto h = __builtin_amdgcn_cvt_pkrtz(a, b);
  return __builtin_bit_cast(unsigned, h);
}
static __device__ __forceinline__ h2 u2h2(unsigned u) { return __builtin_bit_cast(h2, u); }
static __device__ __forceinline__ unsigned h2u(h2 h) { return __builtin_bit_cast(unsigned, h); }
static __device__ __forceinline__ h2 splat_lo(unsigned u) {
  unsigned v = (u & 0xffffu) | (u << 16); return u2h2(v);
}
static __device__ __forceinline__ h2 splat_hi(unsigned u) {
  unsigned v = (u >> 16) | (u & 0xffff0000u); return u2h2(v);
}

// ---------------- kernel 0: weight prep ----------------
__global__ __launch_bounds__(256) void prep_w(
    const float* __restrict__ w_off, const float* __restrict__ w_def,
    _Float16* __restrict__ woff, _Float16* __restrict__ wdef) {
  int idx = blockIdx.x * 256 + threadIdx.x;
  int stride = gridDim.x * 256;
  // wdef A-frags (16x16x32, standard k): [kk9][ks4][ot8][lane64][j8]
  //   o = ot*16 + (lane&15); c = ks*32 + (lane>>4)*8 + j
  for (int i = idx; i < 147456; i += stride) {
    int j = i & 7, l = (i >> 3) & 63, ot = (i >> 9) & 7, ks = (i >> 12) & 3, kk = i >> 14;
    int o = ot * 16 + (l & 15);
    int c = ks * 32 + ((l >> 4) << 3) + j;
    wdef[i] = (_Float16)w_def[(o * 128 + c) * 9 + kk];
  }
  // woff A-frags (16x16x32): [ks4][mt5][lane64][j8], rows>=72 zero
  for (int i = idx; i < 10240; i += stride) {
    int j = i & 7, l = (i >> 3) & 63, t = i >> 9;
    int mt = t % 5, ks = t / 5;
    int o = mt * 16 + (l & 15);
    int c = ks * 32 + ((l >> 4) << 3) + j;
    woff[i] = (o < 72) ? (_Float16)w_off[o * 128 + c] : (_Float16)0.f;
  }
}

// ---------------- kernel 1: offset conv, f16 MFMA ----------------
__global__ __launch_bounds__(256) void offset_conv(
    const float* __restrict__ x, const _Float16* __restrict__ woff,
    const float* __restrict__ b_off, unsigned* __restrict__ offs2) {
  __shared__ uint2 xpk[32 * 128];   // 32 KB
  int tid = threadIdx.x, lane = tid & 63, wv = tid >> 6;
  int i = blockIdx.x;
  int L = (i & 7) * 64 + (i >> 3);  // XCD band swizzle
  int b = L >> 7, h = L & 127;

#pragma unroll
  for (int it = 0; it < 4; it++) {
    int u = it * 256 + tid;
    int px4 = u & 31, cqq = u >> 5;   // 32 px-quads x 32 ch-quads
    const float* xp = x + (((size_t)b * 128 + cqq * 4) * 128 + h) * 128 + px4 * 4;
    float4 v0 = *(const float4*)xp;
    float4 v1 = *(const float4*)(xp + HW);
    float4 v2 = *(const float4*)(xp + 2 * HW);
    float4 v3 = *(const float4*)(xp + 3 * HW);
    uint2* dst = &xpk[cqq * 128 + px4 * 4];
    uint2 w;
    w.x = pkrtz(v0.x, v1.x); w.y = pkrtz(v2.x, v3.x); dst[0] = w;
    w.x = pkrtz(v0.y, v1.y); w.y = pkrtz(v2.y, v3.y); dst[1] = w;
    w.x = pkrtz(v0.z, v1.z); w.y = pkrtz(v2.z, v3.z); dst[2] = w;
    w.x = pkrtz(v0.w, v1.w); w.y = pkrtz(v2.w, v3.w); dst[3] = w;
  }
  __syncthreads();

  floatx4 acc[5][2];
#pragma unroll
  for (int mt = 0; mt < 5; mt++) { acc[mt][0] = (floatx4)0.f; acc[mt][1] = (floatx4)0.f; }
  const h8* A = (const h8*)woff;
  int quad = lane >> 4, col = lane & 15;
#pragma unroll
  for (int ks = 0; ks < 4; ks++) {
#pragma unroll
    for (int nn = 0; nn < 2; nn++) {
      int px = (2 * wv + nn) * 16 + col;
      int cq2 = ks * 8 + quad * 2;
      uint2 lo = xpk[cq2 * 128 + px];
      uint2 hi = xpk[(cq2 + 1) * 128 + px];
      uint4 q; q.x = lo.x; q.y = lo.y; q.z = hi.x; q.w = hi.y;
      h8 bv = __builtin_bit_cast(h8, q);
#pragma unroll
      for (int mt = 0; mt < 5; mt++)
        acc[mt][nn] = __builtin_amdgcn_mfma_f32_16x16x32_f16(A[(ks * 5 + mt) * 64 + lane], bv, acc[mt][nn], 0, 0, 0);
    }
  }
#pragma unroll
  for (int mt = 0; mt < 5; mt++) {
    if (mt == 4 && quad >= 2) continue;   // rows 72..79 padding
    int o0 = mt * 16 + quad * 4;
    float4 bo = *(const float4*)(b_off + o0);
#pragma unroll
    for (int nn = 0; nn < 2; nn++) {
      floatx4 f = acc[mt][nn];
      int pp = (2 * wv + nn) * 16 + col;
      unsigned* dst = offs2 + ((size_t)b * 36 + (o0 >> 1)) * HW + h * 128 + pp;
      dst[0]  = pkrtz(f[0] + bo.x, f[1] + bo.y);
      dst[HW] = pkrtz(f[2] + bo.z, f[3] + bo.w);
    }
  }
}

// ---------------- kernel 2: deform conv ----------------
__global__ __launch_bounds__(256, 3) void deform_conv(
    const float* __restrict__ x, const _Float16* __restrict__ wdef,
    const unsigned* __restrict__ offs2, float* __restrict__ out) {
  __shared__ uint4 xs4[7 * 74 * 4];     // [r][px][slot] 8-ch f16 octets, 33152 B
  __shared__ uint4 bfrag[2][256];       // [nt4][lane64] K=32 B-frags, 8192 B
  __shared__ unsigned rec_a[576];       // [kk9][px64]: lx | r0<<8 | r1<<12
  __shared__ uint2 rec_w[576];          // {pk(wy0,wy1), pk(wA,wB)}

  int tid = threadIdx.x, lane = tid & 63, wv = tid >> 6;
  int i = blockIdx.x;
  int L = (i & 7) * 128 + (i >> 3);     // XCD band swizzle
  int half = L & 1, h = (L >> 1) & 127, b = L >> 8;
  int p0 = half * 64;
  int rlo = min(max(h - 3, 0), 121);    // staged rows rlo..rlo+6
  int cs = p0 - 4;                      // staged col start (global px)

  floatx4 acc[8];
#pragma unroll
  for (int ot = 0; ot < 8; ot++) acc[ot] = (floatx4)0.f;

  for (int t = 0; t < 4; t++) {         // group t: channels [32t, 32t+32)
    __syncthreads();                    // prev group's xs/rec readers done
    // ---- records: 9 kk x 64 px ----
#pragma unroll
    for (int it = 0; it < 3; it++) {
      int u = tid + it * 256;
      if (u < 576) {
        int kk = u >> 6, pl = u & 63;
        int p = p0 + pl;
        unsigned dd = offs2[((size_t)b * 36 + t * 9 + kk) * HW + h * 128 + p];
        h2 d = u2h2(dd);
        float dy = (float)d[0], dx = (float)d[1];
        float py = (float)h + (float)(kk / 3 - 1) + dy;
        float pxs = (float)p + (float)(kk % 3 - 1) + dx;
        float y0f = floorf(py), x0f = floorf(pxs);
        int y0 = (int)y0f, x0 = (int)x0f;
        float wy1 = py - y0f, wx1 = pxs - x0f;
        float wy0 = 1.f - wy1, wx0 = 1.f - wx1;
        int x1 = x0 + 1, y1 = y0 + 1;
        int xb = min(max(x0, 0), 126);
        float fx0 = (x0 >= 0 && x0 <= 127) ? 1.f : 0.f;
        float fx1 = (x1 >= 0 && x1 <= 127) ? 1.f : 0.f;
        float wA = (x0 == xb ? wx0 * fx0 : 0.f) + (x1 == xb ? wx1 * fx1 : 0.f);
        float wB = (x0 == xb + 1 ? wx0 * fx0 : 0.f) + (x1 == xb + 1 ? wx1 * fx1 : 0.f);
        float fy0 = (y0 >= 0 && y0 <= 127) ? 1.f : 0.f;
        float fy1 = (y1 >= 0 && y1 <= 127) ? 1.f : 0.f;
        int r0 = min(max(min(max(y0, 0), 127) - rlo, 0), 6);
        int r1 = min(max(min(max(y1, 0), 127) - rlo, 0), 6);
        int lx = min(max(xb - cs, 0), 70);
        rec_a[u] = (unsigned)lx | ((unsigned)r0 << 8) | ((unsigned)r1 << 12);
        uint2 rw;
        rw.x = pkrtz(wy0 * fy0, wy1 * fy1);
        rw.y = pkrtz(wA, wB);
        rec_w[u] = rw;
      }
    }
    // ---- stage x[b][32t..32t+32)[rlo..+6][cs..cs+71] -> xs4 ----
#pragma unroll
    for (int it = 0; it < 2; it++) {
      int u = tid + it * 256;
      if (u < 504) {
        int g4 = u % 18, r = (u / 18) % 7, dq = u / 126;
        int sp = min(max(cs + 4 * g4, 0), 124);   // edge clamp; clamped px never read
        const float* xp = x + (((size_t)b * 128 + t * 32 + dq * 8) * 128 + (rlo + r)) * 128 + sp;
        float4 v[8];
#pragma unroll
        for (int j = 0; j < 8; j++) v[j] = *(const float4*)(xp + (size_t)j * HW);
        const float* vf = (const float*)v;
#pragma unroll
        for (int ii = 0; ii < 4; ii++) {
          uint4 q;
          q.x = pkrtz(vf[0 * 4 + ii], vf[1 * 4 + ii]);
          q.y = pkrtz(vf[2 * 4 + ii], vf[3 * 4 + ii]);
          q.z = pkrtz(vf[4 * 4 + ii], vf[5 * 4 + ii]);
          q.w = pkrtz(vf[6 * 4 + ii], vf[7 * 4 + ii]);
          int px = 4 * g4 + ii;
          int slot = (dq + px + (px >> 2)) & 3;   // bank-quad swizzle
          xs4[(r * 74 + px) * 4 + slot] = q;
        }
      }
    }
    __syncthreads();

    int pxg = lane;          // gather: px = lane, octet dq = wave
    int dq = wv;
    for (int kk = 0; kk < 9; kk++) {
      unsigned aw = rec_a[kk * 64 + pxg];
      uint2 rw = rec_w[kk * 64 + pxg];
      int lx = aw & 0xff, r0 = (aw >> 8) & 0xf, r1 = aw >> 12;
      int lx1 = lx + 1;
      int s0 = (dq + lx + (lx >> 2)) & 3;
      int s1 = (dq + lx1 + (lx1 >> 2)) & 3;
      uint4 P = xs4[(r0 * 74 + lx) * 4 + s0];
      uint4 Q = xs4[(r0 * 74 + lx1) * 4 + s1];
      uint4 R = xs4[(r1 * 74 + lx) * 4 + s0];
      uint4 S = xs4[(r1 * 74 + lx1) * 4 + s1];
      h2 wy0 = splat_lo(rw.x), wy1 = splat_hi(rw.x);
      h2 wA = splat_lo(rw.y), wB = splat_hi(rw.y);
      uint4 bq;
      bq.x = h2u(wy0 * (wA * u2h2(P.x) + wB * u2h2(Q.x)) + wy1 * (wA * u2h2(R.x) + wB * u2h2(S.x)));
      bq.y = h2u(wy0 * (wA * u2h2(P.y) + wB * u2h2(Q.y)) + wy1 * (wA * u2h2(R.y) + wB * u2h2(S.y)));
      bq.z = h2u(wy0 * (wA * u2h2(P.z) + wB * u2h2(Q.z)) + wy1 * (wA * u2h2(R.z) + wB * u2h2(S.z)));
      bq.w = h2u(wy0 * (wA * u2h2(P.w) + wB * u2h2(Q.w)) + wy1 * (wA * u2h2(R.w) + wB * u2h2(S.w)));
      bfrag[kk & 1][(pxg >> 4) * 64 + dq * 16 + (pxg & 15)] = bq;
      __syncthreads();
      // MFMA: wave wv -> N-tile nt=wv, all 8 o-tiles
      const uint4* Ak = (const uint4*)wdef + (size_t)((kk * 4 + t) * 8) * 64;
      h8 bv = __builtin_bit_cast(h8, bfrag[kk & 1][wv * 64 + lane]);
#pragma unroll
      for (int ot = 0; ot < 8; ot++) {
        h8 av = __builtin_bit_cast(h8, Ak[ot * 64 + lane]);
        acc[ot] = __builtin_amdgcn_mfma_f32_16x16x32_f16(av, bv, acc[ot], 0, 0, 0);
      }
    }
  }

  // ---- epilogue: C/D col=lane&15 (px), row=(lane>>4)*4+reg (o); ReLU ----
  int quad = lane >> 4, col = lane & 15;
  float* ob = out + (size_t)b * 128 * HW + h * 128 + p0 + wv * 16 + col;
#pragma unroll
  for (int ot = 0; ot < 8; ot++) {
    floatx4 f = acc[ot];
#pragma unroll
    for (int reg = 0; reg < 4; reg++) {
      int o = ot * 16 + quad * 4 + reg;
      ob[(size_t)o * HW] = fmaxf(f[reg], 0.f);
    }
  }
}

extern "C" void kernel_launch(void* const* d_in, const int* in_sizes, int n_in,
                              void* d_out, int out_size, void* d_ws, size_t ws_size,
                              hipStream_t stream) {
  const float* x     = (const float*)d_in[0];
  const float* w_off = (const float*)d_in[1];
  const float* b_off = (const float*)d_in[2];
  const float* w_def = (const float*)d_in[3];
  float* out = (float*)d_out;

  _Float16* wdef = (_Float16*)d_ws;                          // 294912 B
  _Float16* woff = (_Float16*)((char*)d_ws + 294912);        // 20480 B
  unsigned* offs2 = (unsigned*)((char*)d_ws + 315392);       // 9437184 B

  hipLaunchKernelGGL(prep_w, dim3(288), dim3(256), 0, stream, w_off, w_def, woff, wdef);
  hipLaunchKernelGGL(offset_conv, dim3(512), dim3(256), 0, stream, x, woff, b_off, offs2);
  hipLaunchKernelGGL(deform_conv, dim3(1024), dim3(256), 0, stream, x, wdef, offs2, out);
}

// Round 7
// 184.364 us; speedup vs baseline: 1.1955x; 1.0362x over previous
//
#include <hip/hip_runtime.h>
#include <hip/hip_fp16.h>

// FeatureAdaption (DCNv1). B=4, CIN=COUT=128, H=W=128, K=3, G=4, CG=32.
// Round 7: barrier-free gather->MFMA.
//  - Each thread gathers ITS OWN B-frag operand: pxl = wv*16+(lane&15),
//    ch-octet q = lane>>4. 4 x ds_read_b128 + v_pk bilinear -> h8 operand in
//    registers -> MFMA directly. No bfrag LDS round-trip, no per-kk barriers
//    (round 6's 36 block-wide barriers were the bottleneck: MfmaUtil 6.8%,
//    VALUBusy 19.6% -- both pipes idle at barriers).
//  - xs4 padded: 5 uint4 per pixel (20-word stride) -> gather bank-quad
//    (2r+5px+q)%8 uniform = conflict-free minimum. Staging u->(dq=u&3,g4,r)
//    makes staging writes bank-uniform too.
//  - 2 barriers per 32-ch group (8 total). LDS 48.4 KB -> 3 blocks/CU.
//  - offset_conv: grid 1024 half-row blocks (was 512 full-row), LDS 16 KB.
//
// ws layout (bytes): wdef [0,294912) | woff [294912,315392) | offs2 [315392,9752576)

#define HW 16384

typedef _Float16 h2 __attribute__((ext_vector_type(2)));
typedef _Float16 h8 __attribute__((ext_vector_type(8)));
typedef float floatx4 __attribute__((ext_vector_type(4)));

static __device__ __forceinline__ unsigned pkrtz(float a, float b) {
  auto h = __builtin_amdgcn_cvt_pkrtz(a, b);
  return __builtin_bit_cast(unsigned, h);
}
static __device__ __forceinline__ h2 u2h2(unsigned u) { return __builtin_bit_cast(h2, u); }
static __device__ __forceinline__ unsigned h2u(h2 h) { return __builtin_bit_cast(unsigned, h); }
static __device__ __forceinline__ h2 splat_lo(unsigned u) {
  unsigned v = (u & 0xffffu) | (u << 16); return u2h2(v);
}
static __device__ __forceinline__ h2 splat_hi(unsigned u) {
  unsigned v = (u >> 16) | (u & 0xffff0000u); return u2h2(v);
}

// ---------------- kernel 0: weight prep ----------------
__global__ __launch_bounds__(256) void prep_w(
    const float* __restrict__ w_off, const float* __restrict__ w_def,
    _Float16* __restrict__ woff, _Float16* __restrict__ wdef) {
  int idx = blockIdx.x * 256 + threadIdx.x;
  int stride = gridDim.x * 256;
  // wdef A-frags (16x16x32): [kk9][ks4][ot8][lane64][j8]
  //   o = ot*16 + (lane&15); c = ks*32 + (lane>>4)*8 + j
  for (int i = idx; i < 147456; i += stride) {
    int j = i & 7, l = (i >> 3) & 63, ot = (i >> 9) & 7, ks = (i >> 12) & 3, kk = i >> 14;
    int o = ot * 16 + (l & 15);
    int c = ks * 32 + ((l >> 4) << 3) + j;
    wdef[i] = (_Float16)w_def[(o * 128 + c) * 9 + kk];
  }
  // woff A-frags (16x16x32): [ks4][mt5][lane64][j8], rows>=72 zero
  for (int i = idx; i < 10240; i += stride) {
    int j = i & 7, l = (i >> 3) & 63, t = i >> 9;
    int mt = t % 5, ks = t / 5;
    int o = mt * 16 + (l & 15);
    int c = ks * 32 + ((l >> 4) << 3) + j;
    woff[i] = (o < 72) ? (_Float16)w_off[o * 128 + c] : (_Float16)0.f;
  }
}

// ---------------- kernel 1: offset conv, f16 MFMA, half-row blocks ----------------
__global__ __launch_bounds__(256) void offset_conv(
    const float* __restrict__ x, const _Float16* __restrict__ woff,
    const float* __restrict__ b_off, unsigned* __restrict__ offs2) {
  __shared__ uint2 xpk[32 * 64];    // [cq32][px64] f16 ch-quads, 16 KB
  int tid = threadIdx.x, lane = tid & 63, wv = tid >> 6;
  int i = blockIdx.x;
  int L = (i & 7) * 128 + (i >> 3); // XCD band swizzle
  int half = L & 1, h = (L >> 1) & 127, b = L >> 8;
  int p0 = half * 64;

#pragma unroll
  for (int it = 0; it < 2; it++) {
    int u = it * 256 + tid;
    int px4 = u & 15, cqq = u >> 4;   // 16 px-quads x 32 ch-quads
    const float* xp = x + (((size_t)b * 128 + cqq * 4) * 128 + h) * 128 + p0 + px4 * 4;
    float4 v0 = *(const float4*)xp;
    float4 v1 = *(const float4*)(xp + HW);
    float4 v2 = *(const float4*)(xp + 2 * HW);
    float4 v3 = *(const float4*)(xp + 3 * HW);
    uint2* dst = &xpk[cqq * 64 + px4 * 4];
    uint2 w;
    w.x = pkrtz(v0.x, v1.x); w.y = pkrtz(v2.x, v3.x); dst[0] = w;
    w.x = pkrtz(v0.y, v1.y); w.y = pkrtz(v2.y, v3.y); dst[1] = w;
    w.x = pkrtz(v0.z, v1.z); w.y = pkrtz(v2.z, v3.z); dst[2] = w;
    w.x = pkrtz(v0.w, v1.w); w.y = pkrtz(v2.w, v3.w); dst[3] = w;
  }
  __syncthreads();

  floatx4 acc[5];
#pragma unroll
  for (int mt = 0; mt < 5; mt++) acc[mt] = (floatx4)0.f;
  const h8* A = (const h8*)woff;
  int quad = lane >> 4, col = lane & 15;
  int pxl = wv * 16 + col;
#pragma unroll
  for (int ks = 0; ks < 4; ks++) {
    int cq2 = ks * 8 + quad * 2;
    uint2 lo = xpk[cq2 * 64 + pxl];
    uint2 hi = xpk[(cq2 + 1) * 64 + pxl];
    uint4 qq; qq.x = lo.x; qq.y = lo.y; qq.z = hi.x; qq.w = hi.y;
    h8 bv = __builtin_bit_cast(h8, qq);
#pragma unroll
    for (int mt = 0; mt < 5; mt++)
      acc[mt] = __builtin_amdgcn_mfma_f32_16x16x32_f16(A[(ks * 5 + mt) * 64 + lane], bv, acc[mt], 0, 0, 0);
  }
#pragma unroll
  for (int mt = 0; mt < 5; mt++) {
    if (mt == 4 && quad >= 2) continue;   // rows 72..79 padding
    int o0 = mt * 16 + quad * 4;
    float4 bo = *(const float4*)(b_off + o0);
    floatx4 f = acc[mt];
    unsigned* dst = offs2 + ((size_t)b * 36 + (o0 >> 1)) * HW + h * 128 + p0 + pxl;
    dst[0]  = pkrtz(f[0] + bo.x, f[1] + bo.y);
    dst[HW] = pkrtz(f[2] + bo.z, f[3] + bo.w);
  }
}

// ---------------- kernel 2: deform conv, barrier-free gather->MFMA ----------------
__global__ __launch_bounds__(256, 3) void deform_conv(
    const float* __restrict__ x, const _Float16* __restrict__ wdef,
    const unsigned* __restrict__ offs2, float* __restrict__ out) {
  __shared__ uint4 xs4[7 * 74 * 5];     // [r][px][slot0..3+pad] 41440 B
  __shared__ unsigned rec_a[576];       // [kk9][px64]: lx | r0<<8 | r1<<12
  __shared__ uint2 rec_w[576];          // {pk(wy0,wy1), pk(wA,wB)}

  int tid = threadIdx.x, lane = tid & 63, wv = tid >> 6;
  int i = blockIdx.x;
  int L = (i & 7) * 128 + (i >> 3);     // XCD band swizzle
  int half = L & 1, h = (L >> 1) & 127, b = L >> 8;
  int p0 = half * 64;
  int rlo = min(max(h - 3, 0), 121);    // staged rows rlo..rlo+6
  int cs = p0 - 4;                      // staged col start (global px)
  int pxl = wv * 16 + (lane & 15);      // this thread's B-frag pixel (0..63)
  int q = lane >> 4;                    // this thread's k-octet (8 channels)

  floatx4 acc[8];
#pragma unroll
  for (int ot = 0; ot < 8; ot++) acc[ot] = (floatx4)0.f;

  for (int t = 0; t < 4; t++) {         // group t: channels [32t, 32t+32)
    __syncthreads();                    // prev group's gathers done before overwrite
    // ---- records: 9 kk x 64 px ----
#pragma unroll
    for (int it = 0; it < 3; it++) {
      int u = tid + it * 256;
      if (u < 576) {
        int kk = u >> 6, pl = u & 63;
        int p = p0 + pl;
        unsigned dd = offs2[((size_t)b * 36 + t * 9 + kk) * HW + h * 128 + p];
        h2 d = u2h2(dd);
        float dy = (float)d[0], dx = (float)d[1];
        float py = (float)h + (float)(kk / 3 - 1) + dy;
        float pxs = (float)p + (float)(kk % 3 - 1) + dx;
        float y0f = floorf(py), x0f = floorf(pxs);
        int y0 = (int)y0f, x0 = (int)x0f;
        float wy1 = py - y0f, wx1 = pxs - x0f;
        float wy0 = 1.f - wy1, wx0 = 1.f - wx1;
        int x1 = x0 + 1, y1 = y0 + 1;
        int xb = min(max(x0, 0), 126);
        float fx0 = (x0 >= 0 && x0 <= 127) ? 1.f : 0.f;
        float fx1 = (x1 >= 0 && x1 <= 127) ? 1.f : 0.f;
        float wA = (x0 == xb ? wx0 * fx0 : 0.f) + (x1 == xb ? wx1 * fx1 : 0.f);
        float wB = (x0 == xb + 1 ? wx0 * fx0 : 0.f) + (x1 == xb + 1 ? wx1 * fx1 : 0.f);
        float fy0 = (y0 >= 0 && y0 <= 127) ? 1.f : 0.f;
        float fy1 = (y1 >= 0 && y1 <= 127) ? 1.f : 0.f;
        int r0 = min(max(min(max(y0, 0), 127) - rlo, 0), 6);
        int r1 = min(max(min(max(y1, 0), 127) - rlo, 0), 6);
        int lx = min(max(xb - cs, 0), 70);
        rec_a[u] = (unsigned)lx | ((unsigned)r0 << 8) | ((unsigned)r1 << 12);
        uint2 rw;
        rw.x = pkrtz(wy0 * fy0, wy1 * fy1);
        rw.y = pkrtz(wA, wB);
        rec_w[u] = rw;
      }
    }
    // ---- stage x[b][32t..+32)[rlo..+6][cs..cs+71] -> xs4 ----
    // u -> dq=u&3, g4=(u>>2)%18, r=u/72: staging write banks uniform
#pragma unroll
    for (int it = 0; it < 2; it++) {
      int u = tid + it * 256;
      if (u < 504) {
        int dq = u & 3, g4 = (u >> 2) % 18, r = u / 72;
        int sp = min(max(cs + 4 * g4, 0), 124);   // edge clamp; clamped px never read
        const float* xp = x + (((size_t)b * 128 + t * 32 + dq * 8) * 128 + (rlo + r)) * 128 + sp;
        float4 v[8];
#pragma unroll
        for (int j = 0; j < 8; j++) v[j] = *(const float4*)(xp + (size_t)j * HW);
        const float* vf = (const float*)v;
#pragma unroll
        for (int ii = 0; ii < 4; ii++) {
          uint4 qq;
          qq.x = pkrtz(vf[0 * 4 + ii], vf[1 * 4 + ii]);
          qq.y = pkrtz(vf[2 * 4 + ii], vf[3 * 4 + ii]);
          qq.z = pkrtz(vf[4 * 4 + ii], vf[5 * 4 + ii]);
          qq.w = pkrtz(vf[6 * 4 + ii], vf[7 * 4 + ii]);
          int px = 4 * g4 + ii;
          xs4[(r * 74 + px) * 5 + dq] = qq;
        }
      }
    }
    __syncthreads();

    // ---- 9 kk: per-thread gather -> own B-frag operand -> MFMA. NO barriers ----
#pragma unroll
    for (int kk = 0; kk < 9; kk++) {
      unsigned aw = rec_a[kk * 64 + pxl];     // 4-way same-address broadcast
      uint2 rw = rec_w[kk * 64 + pxl];
      int lx = aw & 0xff, r0 = (aw >> 8) & 0xf, r1 = (int)(aw >> 12);
      const uint4* e0 = &xs4[(r0 * 74 + lx) * 5 + q];
      const uint4* e1 = &xs4[(r1 * 74 + lx) * 5 + q];
      uint4 P = e0[0], Q = e0[5], R = e1[0], S = e1[5];
      h2 wy0 = splat_lo(rw.x), wy1 = splat_hi(rw.x);
      h2 wA = splat_lo(rw.y), wB = splat_hi(rw.y);
      uint4 bq;
      bq.x = h2u(wy0 * (wA * u2h2(P.x) + wB * u2h2(Q.x)) + wy1 * (wA * u2h2(R.x) + wB * u2h2(S.x)));
      bq.y = h2u(wy0 * (wA * u2h2(P.y) + wB * u2h2(Q.y)) + wy1 * (wA * u2h2(R.y) + wB * u2h2(S.y)));
      bq.z = h2u(wy0 * (wA * u2h2(P.z) + wB * u2h2(Q.z)) + wy1 * (wA * u2h2(R.z) + wB * u2h2(S.z)));
      bq.w = h2u(wy0 * (wA * u2h2(P.w) + wB * u2h2(Q.w)) + wy1 * (wA * u2h2(R.w) + wB * u2h2(S.w)));
      h8 bv = __builtin_bit_cast(h8, bq);
      const uint4* Ak = (const uint4*)wdef + (size_t)(kk * 2048 + t * 512);
#pragma unroll
      for (int ot = 0; ot < 8; ot++) {
        h8 av = __builtin_bit_cast(h8, Ak[ot * 64 + lane]);
        acc[ot] = __builtin_amdgcn_mfma_f32_16x16x32_f16(av, bv, acc[ot], 0, 0, 0);
      }
    }
  }

  // ---- epilogue: C/D col=lane&15 (px), row=(lane>>4)*4+reg (o); ReLU ----
  float* ob = out + (size_t)b * 128 * HW + h * 128 + p0 + pxl;
#pragma unroll
  for (int ot = 0; ot < 8; ot++) {
    floatx4 f = acc[ot];
#pragma unroll
    for (int reg = 0; reg < 4; reg++) {
      int o = ot * 16 + q * 4 + reg;
      ob[(size_t)o * HW] = fmaxf(f[reg], 0.f);
    }
  }
}

extern "C" void kernel_launch(void* const* d_in, const int* in_sizes, int n_in,
                              void* d_out, int out_size, void* d_ws, size_t ws_size,
                              hipStream_t stream) {
  const float* x     = (const float*)d_in[0];
  const float* w_off = (const float*)d_in[1];
  const float* b_off = (const float*)d_in[2];
  const float* w_def = (const float*)d_in[3];
  float* out = (float*)d_out;

  _Float16* wdef = (_Float16*)d_ws;                          // 294912 B
  _Float16* woff = (_Float16*)((char*)d_ws + 294912);        // 20480 B
  unsigned* offs2 = (unsigned*)((char*)d_ws + 315392);       // 9437184 B

  hipLaunchKernelGGL(prep_w, dim3(288), dim3(256), 0, stream, w_off, w_def, woff, wdef);
  hipLaunchKernelGGL(offset_conv, dim3(1024), dim3(256), 0, stream, x, woff, b_off, offs2);
  hipLaunchKernelGGL(deform_conv, dim3(1024), dim3(256), 0, stream, x, wdef, offs2, out);
}

// Round 8
// 178.447 us; speedup vs baseline: 1.2352x; 1.0332x over previous
//
#include <hip/hip_runtime.h>
#include <hip/hip_fp16.h>

// FeatureAdaption (DCNv1). B=4, CIN=COUT=128, H=W=128, K=3, G=4, CG=32.
// Round 8: occupancy + DMA staging + fused prep.
//  - deform: 5-row slab (|dy|<1 window, clamped), xs 23.5 KB, LDS 30.5 KB
//    -> 5 blocks/CU (was 3). launch_bounds(256,5).
//  - x16[b][h][w][c] f16 (channel-last) written by fused prep_row kernel;
//    deform stages via __builtin_amdgcn_global_load_lds width=16 (no VALU
//    pack, no staging VGPRs). Runtime ws_size check; f32-pack fallback.
//  - prep_row = x row f32 -> LDS -> {x16 write + offset GEMM} (one x pass).
//
// ws layout (bytes): wdef [0,294912) | woff [294912,315392)
//   | offs2 [315392,9752576) | x16 [9752576,26529792)  (x16 only if ws fits)

#define HW 16384

typedef _Float16 h2 __attribute__((ext_vector_type(2)));
typedef _Float16 h8 __attribute__((ext_vector_type(8)));
typedef float floatx4 __attribute__((ext_vector_type(4)));

static __device__ __forceinline__ unsigned pkrtz(float a, float b) {
  auto h = __builtin_amdgcn_cvt_pkrtz(a, b);
  return __builtin_bit_cast(unsigned, h);
}
static __device__ __forceinline__ h2 u2h2(unsigned u) { return __builtin_bit_cast(h2, u); }
static __device__ __forceinline__ unsigned h2u(h2 h) { return __builtin_bit_cast(unsigned, h); }
static __device__ __forceinline__ h2 splat_lo(unsigned u) {
  unsigned v = (u & 0xffffu) | (u << 16); return u2h2(v);
}
static __device__ __forceinline__ h2 splat_hi(unsigned u) {
  unsigned v = (u >> 16) | (u & 0xffff0000u); return u2h2(v);
}
static __device__ __forceinline__ void async16(const void* g, void* l) {
  __builtin_amdgcn_global_load_lds(
      (const __attribute__((address_space(1))) unsigned*)g,
      (__attribute__((address_space(3))) unsigned*)l, 16, 0, 0);
}

// ---------------- kernel 0: weight prep ----------------
__global__ __launch_bounds__(256) void prep_w(
    const float* __restrict__ w_off, const float* __restrict__ w_def,
    _Float16* __restrict__ woff, _Float16* __restrict__ wdef) {
  int idx = blockIdx.x * 256 + threadIdx.x;
  int stride = gridDim.x * 256;
  // wdef A-frags (16x16x32): [kk9][ks4][ot8][lane64][j8]
  for (int i = idx; i < 147456; i += stride) {
    int j = i & 7, l = (i >> 3) & 63, ot = (i >> 9) & 7, ks = (i >> 12) & 3, kk = i >> 14;
    int o = ot * 16 + (l & 15);
    int c = ks * 32 + ((l >> 4) << 3) + j;
    wdef[i] = (_Float16)w_def[(o * 128 + c) * 9 + kk];
  }
  // woff A-frags (16x16x32): [ks4][mt5][lane64][j8], rows>=72 zero
  for (int i = idx; i < 10240; i += stride) {
    int j = i & 7, l = (i >> 3) & 63, t = i >> 9;
    int mt = t % 5, ks = t / 5;
    int o = mt * 16 + (l & 15);
    int c = ks * 32 + ((l >> 4) << 3) + j;
    woff[i] = (o < 72) ? (_Float16)w_off[o * 128 + c] : (_Float16)0.f;
  }
}

// ---------------- kernel 1: fused transpose + offset conv ----------------
// grid 512 = (b,h) row. Stage x row f32 -> LDS f16; write x16 channel-last;
// offset GEMM (f16 MFMA) -> offs2 packed half2.
template <bool X16>
__global__ __launch_bounds__(256) void prep_row(
    const float* __restrict__ x, const _Float16* __restrict__ woff,
    const float* __restrict__ b_off, unsigned* __restrict__ offs2,
    _Float16* __restrict__ x16) {
  __shared__ uint2 xpk[32 * 128];   // [cq32][px128] f16 ch-quads, 32 KB
  int tid = threadIdx.x, lane = tid & 63, wv = tid >> 6;
  int i = blockIdx.x;
  int L = (i & 7) * 64 + (i >> 3);  // XCD band swizzle
  int b = L >> 7, h = L & 127;

#pragma unroll
  for (int it = 0; it < 4; it++) {
    int u = it * 256 + tid;
    int px4 = u & 31, cqq = u >> 5;   // 32 px-quads x 32 ch-quads
    const float* xp = x + (((size_t)b * 128 + cqq * 4) * 128 + h) * 128 + px4 * 4;
    float4 v0 = *(const float4*)xp;
    float4 v1 = *(const float4*)(xp + HW);
    float4 v2 = *(const float4*)(xp + 2 * HW);
    float4 v3 = *(const float4*)(xp + 3 * HW);
    uint2* dst = &xpk[cqq * 128 + px4 * 4];
    uint2 w;
    w.x = pkrtz(v0.x, v1.x); w.y = pkrtz(v2.x, v3.x); dst[0] = w;
    w.x = pkrtz(v0.y, v1.y); w.y = pkrtz(v2.y, v3.y); dst[1] = w;
    w.x = pkrtz(v0.z, v1.z); w.y = pkrtz(v2.z, v3.z); dst[2] = w;
    w.x = pkrtz(v0.w, v1.w); w.y = pkrtz(v2.w, v3.w); dst[3] = w;
  }
  __syncthreads();

  if (X16) {
    // x16[b][h][px][c]: thread chunk = (px, oct): 16B of 8 consecutive ch
    uint4* xrow = (uint4*)(x16 + (((size_t)b * 128 + h) * 128) * 128);
#pragma unroll
    for (int it = 0; it < 8; it++) {
      int u = it * 256 + tid;
      int oct = u & 15, px = u >> 4;
      uint2 a = xpk[(2 * oct) * 128 + px];
      uint2 c = xpk[(2 * oct + 1) * 128 + px];
      uint4 q; q.x = a.x; q.y = a.y; q.z = c.x; q.w = c.y;
      xrow[px * 16 + oct] = q;      // coalesced: oct fastest
    }
  }

  floatx4 acc[5][2];
#pragma unroll
  for (int mt = 0; mt < 5; mt++) { acc[mt][0] = (floatx4)0.f; acc[mt][1] = (floatx4)0.f; }
  const h8* A = (const h8*)woff;
  int q = lane >> 4, col = lane & 15;
#pragma unroll
  for (int ks = 0; ks < 4; ks++) {
    h8 av[5];
#pragma unroll
    for (int mt = 0; mt < 5; mt++) av[mt] = A[(ks * 5 + mt) * 64 + lane];
#pragma unroll
    for (int nn = 0; nn < 2; nn++) {
      int pxl = (2 * wv + nn) * 16 + col;
      uint2 lo = xpk[(ks * 8 + 2 * q) * 128 + pxl];
      uint2 hi = xpk[(ks * 8 + 2 * q + 1) * 128 + pxl];
      uint4 qq; qq.x = lo.x; qq.y = lo.y; qq.z = hi.x; qq.w = hi.y;
      h8 bv = __builtin_bit_cast(h8, qq);
#pragma unroll
      for (int mt = 0; mt < 5; mt++)
        acc[mt][nn] = __builtin_amdgcn_mfma_f32_16x16x32_f16(av[mt], bv, acc[mt][nn], 0, 0, 0);
    }
  }
#pragma unroll
  for (int mt = 0; mt < 5; mt++) {
    if (mt == 4 && q >= 2) continue;   // rows 72..79 padding
    int o0 = mt * 16 + q * 4;
    float4 bo = *(const float4*)(b_off + o0);
#pragma unroll
    for (int nn = 0; nn < 2; nn++) {
      floatx4 f = acc[mt][nn];
      int pp = (2 * wv + nn) * 16 + col;
      unsigned* dst = offs2 + ((size_t)b * 36 + (o0 >> 1)) * HW + h * 128 + pp;
      dst[0]  = pkrtz(f[0] + bo.x, f[1] + bo.y);
      dst[HW] = pkrtz(f[2] + bo.z, f[3] + bo.w);
    }
  }
}

// ---------------- kernel 2: deform conv ----------------
// grid 1024 = (b,h,half). 5-row slab, 72-px window, xs[r5][px72][oct4] uint4.
// X16: staging via global_load_lds (async DMA). Else: f32 load + pack.
template <bool X16>
__global__ __launch_bounds__(256, 5) void deform_conv(
    const float* __restrict__ x, const _Float16* __restrict__ x16,
    const _Float16* __restrict__ wdef, const unsigned* __restrict__ offs2,
    float* __restrict__ out) {
  __shared__ uint4 xs[1472];            // 23552 B (1440 used + DMA pad)
  __shared__ unsigned rec_a[576];       // [kk9][px64]: lx | r0<<8 | r1<<12
  __shared__ uint2 rec_w[576];          // {pk(wy0,wy1), pk(wA,wB)}

  int tid = threadIdx.x, lane = tid & 63, wv = tid >> 6;
  int i = blockIdx.x;
  int L = (i & 7) * 128 + (i >> 3);     // XCD band swizzle
  int half = L & 1, h = (L >> 1) & 127, b = L >> 8;
  int p0 = half * 64;
  int rlo = min(max(h - 2, 0), 123);    // staged rows rlo..rlo+4
  int cs = p0 - 4;                      // staged col start (global px)
  int pxl = wv * 16 + (lane & 15);      // this thread's B-frag pixel (0..63)
  int q = lane >> 4;                    // this thread's k-octet

  floatx4 acc[8];
#pragma unroll
  for (int ot = 0; ot < 8; ot++) acc[ot] = (floatx4)0.f;

  for (int t = 0; t < 4; t++) {         // group t: channels [32t, 32t+32)
    __syncthreads();                    // prev group's readers done
    // ---- staging: issue first (latency head start) ----
    if (X16) {
      const _Float16* xb16 = x16 + (((size_t)b * 128 + rlo) * 128) * 128 + t * 32;
#pragma unroll
      for (int jj = 0; jj < 6; jj++) {
        int j = wv + 4 * jj;            // wave-uniform instr index
        if (j < 23) {
          int slot = j * 64 + lane;
          int qq = lane & 3;
          int s2 = slot >> 2;
          int r = (s2 * 57) >> 12;      // floor(s2/72), exact for s2<360
          int px = s2 - r * 72;
          r = min(r, 4); px = min(px, 71);
          int pc = min(max(cs + px, 0), 127);
          async16(xb16 + ((size_t)r * 128 + pc) * 128 + qq * 8, &xs[j * 64]);
        }
      }
    } else {
#pragma unroll
      for (int it = 0; it < 2; it++) {
        int u = tid + it * 256;
        if (u < 360) {
          int dq = u & 3, v2 = u >> 2;
          int g4 = v2 % 18, r = v2 / 18;
          int sp = min(max(cs + 4 * g4, 0), 124);
          const float* xp = x + (((size_t)b * 128 + t * 32 + dq * 8) * 128 + (rlo + r)) * 128 + sp;
          float4 v[8];
#pragma unroll
          for (int j = 0; j < 8; j++) v[j] = *(const float4*)(xp + (size_t)j * HW);
          const float* vf = (const float*)v;
#pragma unroll
          for (int ii = 0; ii < 4; ii++) {
            uint4 qq;
            qq.x = pkrtz(vf[0 * 4 + ii], vf[1 * 4 + ii]);
            qq.y = pkrtz(vf[2 * 4 + ii], vf[3 * 4 + ii]);
            qq.z = pkrtz(vf[4 * 4 + ii], vf[5 * 4 + ii]);
            qq.w = pkrtz(vf[6 * 4 + ii], vf[7 * 4 + ii]);
            xs[(r * 72 + 4 * g4 + ii) * 4 + dq] = qq;
          }
        }
      }
    }
    // ---- records: 9 kk x 64 px ----
#pragma unroll
    for (int it = 0; it < 3; it++) {
      int u = tid + it * 256;
      if (u < 576) {
        int kk = u >> 6, pl = u & 63;
        int p = p0 + pl;
        unsigned dd = offs2[((size_t)b * 36 + t * 9 + kk) * HW + h * 128 + p];
        h2 d = u2h2(dd);
        float dy = (float)d[0], dx = (float)d[1];
        float py = (float)h + (float)(kk / 3 - 1) + dy;
        float pxs = (float)p + (float)(kk % 3 - 1) + dx;
        float y0f = floorf(py), x0f = floorf(pxs);
        int y0 = (int)y0f, x0 = (int)x0f;
        float wy1 = py - y0f, wx1 = pxs - x0f;
        float wy0 = 1.f - wy1, wx0 = 1.f - wx1;
        int x1 = x0 + 1, y1 = y0 + 1;
        int xb = min(max(x0, 0), 126);
        float fx0 = (x0 >= 0 && x0 <= 127) ? 1.f : 0.f;
        float fx1 = (x1 >= 0 && x1 <= 127) ? 1.f : 0.f;
        float wA = (x0 == xb ? wx0 * fx0 : 0.f) + (x1 == xb ? wx1 * fx1 : 0.f);
        float wB = (x0 == xb + 1 ? wx0 * fx0 : 0.f) + (x1 == xb + 1 ? wx1 * fx1 : 0.f);
        float fy0 = (y0 >= 0 && y0 <= 127) ? 1.f : 0.f;
        float fy1 = (y1 >= 0 && y1 <= 127) ? 1.f : 0.f;
        int r0 = min(max(min(max(y0, 0), 127) - rlo, 0), 4);
        int r1 = min(max(min(max(y1, 0), 127) - rlo, 0), 4);
        int lx = min(max(xb - cs, 0), 70);
        rec_a[u] = (unsigned)lx | ((unsigned)r0 << 8) | ((unsigned)r1 << 12);
        uint2 rw;
        rw.x = pkrtz(wy0 * fy0, wy1 * fy1);
        rw.y = pkrtz(wA, wB);
        rec_w[u] = rw;
      }
    }
    __syncthreads();   // drains DMA (vmcnt) + LDS writes

    // ---- 9 kk: per-thread gather -> own B operand -> MFMA. No barriers ----
#pragma unroll
    for (int kk = 0; kk < 9; kk++) {
      unsigned aw = rec_a[kk * 64 + pxl];     // 4-way broadcast
      uint2 rw = rec_w[kk * 64 + pxl];
      int lx = aw & 0xff, r0 = (aw >> 8) & 0xf, r1 = (int)(aw >> 12);
      const uint4* e0 = &xs[(r0 * 72 + lx) * 4 + q];
      const uint4* e1 = &xs[(r1 * 72 + lx) * 4 + q];
      uint4 P = e0[0], Q = e0[4], R = e1[0], S = e1[4];
      h2 wy0 = splat_lo(rw.x), wy1 = splat_hi(rw.x);
      h2 wA = splat_lo(rw.y), wB = splat_hi(rw.y);
      uint4 bq;
      bq.x = h2u(wy0 * (wA * u2h2(P.x) + wB * u2h2(Q.x)) + wy1 * (wA * u2h2(R.x) + wB * u2h2(S.x)));
      bq.y = h2u(wy0 * (wA * u2h2(P.y) + wB * u2h2(Q.y)) + wy1 * (wA * u2h2(R.y) + wB * u2h2(S.y)));
      bq.z = h2u(wy0 * (wA * u2h2(P.z) + wB * u2h2(Q.z)) + wy1 * (wA * u2h2(R.z) + wB * u2h2(S.z)));
      bq.w = h2u(wy0 * (wA * u2h2(P.w) + wB * u2h2(Q.w)) + wy1 * (wA * u2h2(R.w) + wB * u2h2(S.w)));
      h8 bv = __builtin_bit_cast(h8, bq);
      const uint4* Ak = (const uint4*)wdef + (size_t)(kk * 2048 + t * 512);
#pragma unroll
      for (int ot = 0; ot < 8; ot++) {
        h8 av = __builtin_bit_cast(h8, Ak[ot * 64 + lane]);
        acc[ot] = __builtin_amdgcn_mfma_f32_16x16x32_f16(av, bv, acc[ot], 0, 0, 0);
      }
    }
  }

  // ---- epilogue: C/D col=lane&15 (px), row=(lane>>4)*4+reg (o); ReLU ----
  float* ob = out + (size_t)b * 128 * HW + h * 128 + p0 + pxl;
#pragma unroll
  for (int ot = 0; ot < 8; ot++) {
    floatx4 f = acc[ot];
#pragma unroll
    for (int reg = 0; reg < 4; reg++) {
      int o = ot * 16 + q * 4 + reg;
      ob[(size_t)o * HW] = fmaxf(f[reg], 0.f);
    }
  }
}

extern "C" void kernel_launch(void* const* d_in, const int* in_sizes, int n_in,
                              void* d_out, int out_size, void* d_ws, size_t ws_size,
                              hipStream_t stream) {
  const float* x     = (const float*)d_in[0];
  const float* w_off = (const float*)d_in[1];
  const float* b_off = (const float*)d_in[2];
  const float* w_def = (const float*)d_in[3];
  float* out = (float*)d_out;

  _Float16* wdef = (_Float16*)d_ws;                          // 294912 B
  _Float16* woff = (_Float16*)((char*)d_ws + 294912);        // 20480 B
  unsigned* offs2 = (unsigned*)((char*)d_ws + 315392);       // 9437184 B
  _Float16* x16  = (_Float16*)((char*)d_ws + 9752576);       // 16777216 B
  bool useX16 = ws_size >= 26529792ull;

  prep_w<<<dim3(288), dim3(256), 0, stream>>>(w_off, w_def, woff, wdef);
  if (useX16) {
    prep_row<true><<<dim3(512), dim3(256), 0, stream>>>(x, woff, b_off, offs2, x16);
    deform_conv<true><<<dim3(1024), dim3(256), 0, stream>>>(x, x16, wdef, offs2, out);
  } else {
    prep_row<false><<<dim3(512), dim3(256), 0, stream>>>(x, woff, b_off, offs2, x16);
    deform_conv<false><<<dim3(1024), dim3(256), 0, stream>>>(x, x16, wdef, offs2, out);
  }
}

// Round 9
// 136.618 us; speedup vs baseline: 1.6133x; 1.3062x over previous
//
#include <hip/hip_runtime.h>
#include <hip/hip_fp16.h>

// FeatureAdaption (DCNv1). B=4, CIN=COUT=128, H=W=128, K=3, G=4, CG=32.
// Round 9: halve A-fragment L1 traffic + kill gather bank conflicts.
//  - deform: grid 512 = (b,h) full row; wave = 32 px (2 B-frags) -> the 8
//    wdef A-loads per phase feed 16 MFMAs (A bytes/px halved; round-8 math:
//    A-traffic was ~30 us of per-CU L1 time, the hidden dominant pipe).
//  - xs: [r5][px136][slot5] uint4, stride 5/px -> gather bank-group
//    (5*lx+q)%8 spans all 8 groups (round 8's DMA-forced stride-4 gave
//    {q,q+4} = 8-way conflicts, 4.16M cycles). Manual staging from
//    channel-last x16 (coalesced oct-fastest), ds_write_b128 swizzle-free.
//  - records recomputed per-lane in registers from preloaded offs2 (18 regs);
//    no rec LDS, no rec barrier, no global load inside the phase chain.
//  - 2 barriers per ch-group (8 total). LDS 54.4 KB, 2 blocks/CU (= grid cap).
//
// ws layout (bytes): wdef [0,294912) | woff [294912,315392)
//   | offs2 [315392,9752576) | x16 [9752576,26529792)

#define HW 16384

typedef _Float16 h2 __attribute__((ext_vector_type(2)));
typedef _Float16 h8 __attribute__((ext_vector_type(8)));
typedef float floatx4 __attribute__((ext_vector_type(4)));

static __device__ __forceinline__ unsigned pkrtz(float a, float b) {
  auto h = __builtin_amdgcn_cvt_pkrtz(a, b);
  return __builtin_bit_cast(unsigned, h);
}
static __device__ __forceinline__ h2 u2h2(unsigned u) { return __builtin_bit_cast(h2, u); }
static __device__ __forceinline__ unsigned h2u(h2 h) { return __builtin_bit_cast(unsigned, h); }
static __device__ __forceinline__ h2 splat_lo(unsigned u) {
  unsigned v = (u & 0xffffu) | (u << 16); return u2h2(v);
}
static __device__ __forceinline__ h2 splat_hi(unsigned u) {
  unsigned v = (u >> 16) | (u & 0xffff0000u); return u2h2(v);
}

// ---------------- kernel 0: weight prep ----------------
__global__ __launch_bounds__(256) void prep_w(
    const float* __restrict__ w_off, const float* __restrict__ w_def,
    _Float16* __restrict__ woff, _Float16* __restrict__ wdef) {
  int idx = blockIdx.x * 256 + threadIdx.x;
  int stride = gridDim.x * 256;
  // wdef A-frags (16x16x32): [kk9][ks4][ot8][lane64][j8]
  for (int i = idx; i < 147456; i += stride) {
    int j = i & 7, l = (i >> 3) & 63, ot = (i >> 9) & 7, ks = (i >> 12) & 3, kk = i >> 14;
    int o = ot * 16 + (l & 15);
    int c = ks * 32 + ((l >> 4) << 3) + j;
    wdef[i] = (_Float16)w_def[(o * 128 + c) * 9 + kk];
  }
  // woff A-frags (16x16x32): [ks4][mt5][lane64][j8], rows>=72 zero
  for (int i = idx; i < 10240; i += stride) {
    int j = i & 7, l = (i >> 3) & 63, t = i >> 9;
    int mt = t % 5, ks = t / 5;
    int o = mt * 16 + (l & 15);
    int c = ks * 32 + ((l >> 4) << 3) + j;
    woff[i] = (o < 72) ? (_Float16)w_off[o * 128 + c] : (_Float16)0.f;
  }
}

// ---------------- kernel 1: fused transpose + offset conv ----------------
__global__ __launch_bounds__(256) void prep_row(
    const float* __restrict__ x, const _Float16* __restrict__ woff,
    const float* __restrict__ b_off, unsigned* __restrict__ offs2,
    _Float16* __restrict__ x16) {
  __shared__ uint2 xpk[32 * 128];   // [cq32][px128] f16 ch-quads, 32 KB
  int tid = threadIdx.x, lane = tid & 63, wv = tid >> 6;
  int i = blockIdx.x;
  int L = (i & 7) * 64 + (i >> 3);  // XCD band swizzle
  int b = L >> 7, h = L & 127;

#pragma unroll
  for (int it = 0; it < 4; it++) {
    int u = it * 256 + tid;
    int px4 = u & 31, cqq = u >> 5;
    const float* xp = x + (((size_t)b * 128 + cqq * 4) * 128 + h) * 128 + px4 * 4;
    float4 v0 = *(const float4*)xp;
    float4 v1 = *(const float4*)(xp + HW);
    float4 v2 = *(const float4*)(xp + 2 * HW);
    float4 v3 = *(const float4*)(xp + 3 * HW);
    uint2* dst = &xpk[cqq * 128 + px4 * 4];
    uint2 w;
    w.x = pkrtz(v0.x, v1.x); w.y = pkrtz(v2.x, v3.x); dst[0] = w;
    w.x = pkrtz(v0.y, v1.y); w.y = pkrtz(v2.y, v3.y); dst[1] = w;
    w.x = pkrtz(v0.z, v1.z); w.y = pkrtz(v2.z, v3.z); dst[2] = w;
    w.x = pkrtz(v0.w, v1.w); w.y = pkrtz(v2.w, v3.w); dst[3] = w;
  }
  __syncthreads();

  // x16[b][h][px][c] channel-last
  uint4* xrow = (uint4*)(x16 + (((size_t)b * 128 + h) * 128) * 128);
#pragma unroll
  for (int it = 0; it < 8; it++) {
    int u = it * 256 + tid;
    int oct = u & 15, px = u >> 4;
    uint2 a = xpk[(2 * oct) * 128 + px];
    uint2 c = xpk[(2 * oct + 1) * 128 + px];
    uint4 qv; qv.x = a.x; qv.y = a.y; qv.z = c.x; qv.w = c.y;
    xrow[px * 16 + oct] = qv;
  }

  floatx4 acc[5][2];
#pragma unroll
  for (int mt = 0; mt < 5; mt++) { acc[mt][0] = (floatx4)0.f; acc[mt][1] = (floatx4)0.f; }
  const h8* A = (const h8*)woff;
  int q = lane >> 4, col = lane & 15;
#pragma unroll
  for (int ks = 0; ks < 4; ks++) {
    h8 av[5];
#pragma unroll
    for (int mt = 0; mt < 5; mt++) av[mt] = A[(ks * 5 + mt) * 64 + lane];
#pragma unroll
    for (int nn = 0; nn < 2; nn++) {
      int pxl = (2 * wv + nn) * 16 + col;
      uint2 lo = xpk[(ks * 8 + 2 * q) * 128 + pxl];
      uint2 hi = xpk[(ks * 8 + 2 * q + 1) * 128 + pxl];
      uint4 qq; qq.x = lo.x; qq.y = lo.y; qq.z = hi.x; qq.w = hi.y;
      h8 bv = __builtin_bit_cast(h8, qq);
#pragma unroll
      for (int mt = 0; mt < 5; mt++)
        acc[mt][nn] = __builtin_amdgcn_mfma_f32_16x16x32_f16(av[mt], bv, acc[mt][nn], 0, 0, 0);
    }
  }
#pragma unroll
  for (int mt = 0; mt < 5; mt++) {
    if (mt == 4 && q >= 2) continue;   // rows 72..79 padding
    int o0 = mt * 16 + q * 4;
    float4 bo = *(const float4*)(b_off + o0);
#pragma unroll
    for (int nn = 0; nn < 2; nn++) {
      floatx4 f = acc[mt][nn];
      int pp = (2 * wv + nn) * 16 + col;
      unsigned* dst = offs2 + ((size_t)b * 36 + (o0 >> 1)) * HW + h * 128 + pp;
      dst[0]  = pkrtz(f[0] + bo.x, f[1] + bo.y);
      dst[HW] = pkrtz(f[2] + bo.z, f[3] + bo.w);
    }
  }
}

// ---------------- kernel 2: deform conv ----------------
// grid 512 = (b,h) full row. Wave = 32 px (frags f=0,1). 5-row slab.
__global__ __launch_bounds__(256, 2) void deform_conv(
    const _Float16* __restrict__ x16, const _Float16* __restrict__ wdef,
    const unsigned* __restrict__ offs2, float* __restrict__ out) {
  __shared__ uint4 xs[5 * 136 * 5];     // [r][px][slot(4 used)] 54400 B

  int tid = threadIdx.x, lane = tid & 63, wv = tid >> 6;
  int i = blockIdx.x;
  int L = (i & 7) * 64 + (i >> 3);      // XCD band swizzle
  int b = L >> 7, h = L & 127;
  int rlo = min(max(h - 2, 0), 123);    // staged rows rlo..rlo+4
  // window cols: global -4..131  (lx = xb + 4)
  int pa = 32 * wv + (lane & 15);       // frag-0 pixel (global col)
  int q = lane >> 4;                    // k-octet

  floatx4 acc[2][8];
#pragma unroll
  for (int f = 0; f < 2; f++)
#pragma unroll
    for (int ot = 0; ot < 8; ot++) acc[f][ot] = (floatx4)0.f;

  for (int t = 0; t < 4; t++) {         // group t: channels [32t, 32t+32)
    __syncthreads();                    // prev group's gathers done
    // ---- preload offsets for all 9 kk x 2 frags (registers) ----
    unsigned dd[9][2];
#pragma unroll
    for (int kk = 0; kk < 9; kk++)
#pragma unroll
      for (int f = 0; f < 2; f++)
        dd[kk][f] = offs2[((size_t)b * 36 + t * 9 + kk) * HW + h * 128 + pa + 16 * f];
    // ---- stage 32ch x 5r x 136px from x16 -> xs (stride-5 px) ----
#pragma unroll
    for (int it = 0; it < 11; it++) {
      int u = tid + it * 256;
      if (u < 2720) {
        int oct = u & 3, v2 = u >> 2;
        int px = v2 % 136, r = v2 / 136;
        int pc = min(max(px - 4, 0), 127);
        const uint4* src = (const uint4*)(x16 + (((size_t)b * 128 + rlo + r) * 128 + pc) * 128 + t * 32) + oct;
        xs[(r * 136 + px) * 5 + oct] = *src;
      }
    }
    __syncthreads();

    // ---- 9 kk phases: records in regs -> gather x2 -> 16 MFMA ----
#pragma unroll
    for (int kk = 0; kk < 9; kk++) {
      const uint4* Ak = (const uint4*)wdef + (size_t)(kk * 2048 + t * 512);
      h8 av[8];
#pragma unroll
      for (int ot = 0; ot < 8; ot++) av[ot] = __builtin_bit_cast(h8, Ak[ot * 64 + lane]);
#pragma unroll
      for (int f = 0; f < 2; f++) {
        int p = pa + 16 * f;
        h2 d = u2h2(dd[kk][f]);
        float dy = (float)d[0], dx = (float)d[1];
        float py = (float)h + (float)(kk / 3 - 1) + dy;
        float pxs = (float)p + (float)(kk % 3 - 1) + dx;
        float y0f = floorf(py), x0f = floorf(pxs);
        int y0 = (int)y0f, x0 = (int)x0f;
        float wy1f = py - y0f, wx1 = pxs - x0f;
        float wy0f = 1.f - wy1f, wx0 = 1.f - wx1;
        int x1 = x0 + 1, y1 = y0 + 1;
        int xb = min(max(x0, 0), 126);
        float fx0 = (x0 >= 0 && x0 <= 127) ? 1.f : 0.f;
        float fx1 = (x1 >= 0 && x1 <= 127) ? 1.f : 0.f;
        float wAf = (x0 == xb ? wx0 * fx0 : 0.f) + (x1 == xb ? wx1 * fx1 : 0.f);
        float wBf = (x0 == xb + 1 ? wx0 * fx0 : 0.f) + (x1 == xb + 1 ? wx1 * fx1 : 0.f);
        float fy0 = (y0 >= 0 && y0 <= 127) ? 1.f : 0.f;
        float fy1 = (y1 >= 0 && y1 <= 127) ? 1.f : 0.f;
        int r0 = min(max(min(max(y0, 0), 127) - rlo, 0), 4);
        int r1 = min(max(min(max(y1, 0), 127) - rlo, 0), 4);
        int lx = xb + 4;                       // window col (cs = -4)
        unsigned wy_pk = pkrtz(wy0f * fy0, wy1f * fy1);
        unsigned wab_pk = pkrtz(wAf, wBf);

        int i0 = (r0 * 136 + lx) * 5 + q;
        int i1 = (r1 * 136 + lx) * 5 + q;
        uint4 P = xs[i0], Q = xs[i0 + 5], R = xs[i1], S = xs[i1 + 5];
        h2 wy0 = splat_lo(wy_pk), wy1 = splat_hi(wy_pk);
        h2 wA = splat_lo(wab_pk), wB = splat_hi(wab_pk);
        uint4 bq;
        bq.x = h2u(wy0 * (wA * u2h2(P.x) + wB * u2h2(Q.x)) + wy1 * (wA * u2h2(R.x) + wB * u2h2(S.x)));
        bq.y = h2u(wy0 * (wA * u2h2(P.y) + wB * u2h2(Q.y)) + wy1 * (wA * u2h2(R.y) + wB * u2h2(S.y)));
        bq.z = h2u(wy0 * (wA * u2h2(P.z) + wB * u2h2(Q.z)) + wy1 * (wA * u2h2(R.z) + wB * u2h2(S.z)));
        bq.w = h2u(wy0 * (wA * u2h2(P.w) + wB * u2h2(Q.w)) + wy1 * (wA * u2h2(R.w) + wB * u2h2(S.w)));
        h8 bv = __builtin_bit_cast(h8, bq);
#pragma unroll
        for (int ot = 0; ot < 8; ot++)
          acc[f][ot] = __builtin_amdgcn_mfma_f32_16x16x32_f16(av[ot], bv, acc[f][ot], 0, 0, 0);
      }
    }
  }

  // ---- epilogue: C/D col=lane&15 (px), row=(lane>>4)*4+reg (o); ReLU ----
#pragma unroll
  for (int f = 0; f < 2; f++) {
    float* ob = out + (size_t)b * 128 * HW + h * 128 + pa + 16 * f;
#pragma unroll
    for (int ot = 0; ot < 8; ot++) {
      floatx4 fv = acc[f][ot];
#pragma unroll
      for (int reg = 0; reg < 4; reg++) {
        int o = ot * 16 + q * 4 + reg;
        ob[(size_t)o * HW] = fmaxf(fv[reg], 0.f);
      }
    }
  }
}

extern "C" void kernel_launch(void* const* d_in, const int* in_sizes, int n_in,
                              void* d_out, int out_size, void* d_ws, size_t ws_size,
                              hipStream_t stream) {
  const float* x     = (const float*)d_in[0];
  const float* w_off = (const float*)d_in[1];
  const float* b_off = (const float*)d_in[2];
  const float* w_def = (const float*)d_in[3];
  float* out = (float*)d_out;

  _Float16* wdef = (_Float16*)d_ws;                          // 294912 B
  _Float16* woff = (_Float16*)((char*)d_ws + 294912);        // 20480 B
  unsigned* offs2 = (unsigned*)((char*)d_ws + 315392);       // 9437184 B
  _Float16* x16  = (_Float16*)((char*)d_ws + 9752576);       // 16777216 B

  prep_w<<<dim3(288), dim3(256), 0, stream>>>(w_off, w_def, woff, wdef);
  prep_row<<<dim3(512), dim3(256), 0, stream>>>(x, woff, b_off, offs2, x16);
  deform_conv<<<dim3(512), dim3(256), 0, stream>>>(x16, wdef, offs2, out);
}